// Round 1
// baseline (261.636 us; speedup 1.0000x reference)
//
#include <hip/hip_runtime.h>
#include <hip/hip_bf16.h>
#include <stdint.h>

// Problem constants
#define Bsz 2048
#define Ssz 200
#define Dsz 128
#define Hsz 4
#define SP  224   // padded S for LDS buffers (7 K-steps of 32 for PV)

typedef __attribute__((ext_vector_type(8))) short short8;
typedef __attribute__((ext_vector_type(4))) float f32x4;
typedef unsigned short ushort_t;
typedef unsigned int uint_t;

// ---- LDS byte offsets (all 16-aligned), total 163,248 <= 163,840 ----
#define KEYS_OFF   0        // [224][128] bf16, swizzled   57,344
#define W1EFF_OFF  57344    // [256][128] bf16, swizzled   65,536
#define H1C_OFF    122880   // [32][256]  bf16, swizzled   16,384
#define W2S_OFF    139264   // [4][32][64] bf16, swizzled  16,384
#define SCW_OFF    155648   // [4][224] f32 scores->w       3,584
#define C1S_OFF    159232   // [256] f32                    1,024
#define QS_OFF     160256   // [128] f32                      512
#define B2S_OFF    160768   // [128] f32                      512
#define W3S_OFF    161280   // [128] f32                      512
#define MASK_OFF   161792   // [224] int                      896
#define COMB_OFF   162688   // [128] f32                      512
#define A1S_OFF    163200
#define A2S_OFF    163216
#define B3S_OFF    163232
#define SMEM_BYTES 163248

__device__ __forceinline__ ushort_t f2bf(float x) {
    union { float f; uint_t u; } v; v.f = x;
    uint_t u = v.u;
    u += 0x7FFFu + ((u >> 16) & 1u);   // round-to-nearest-even
    return (ushort_t)(u >> 16);
}

// ---------- prep: fold W1, transpose Wo, cast W2 ----------
__global__ void prep_kernel(const float* __restrict__ W1, const float* __restrict__ W2,
                            const float* __restrict__ Wo,
                            float* __restrict__ W1sum, float* __restrict__ W1c,
                            float* __restrict__ W1diffT, float* __restrict__ WoT,
                            ushort_t* __restrict__ W2bf) {
    int i = blockIdx.x * blockDim.x + threadIdx.x;
    if (i < 32768) {                       // n in [0,256), j in [0,128)
        int n = i >> 7, j = i & 127;
        float a  = W1[n * 512 + j];        // keys part
        float dd = W1[n * 512 + 384 + j];  // (k - q) part
        W1sum[i] = a + dd;                 // coeff of k
        W1c[i]   = W1[n * 512 + 256 + j];  // coeff of k*q
        W1diffT[j * 256 + n] = W1[n * 512 + 128 + j] - dd;  // coeff of q (transposed)
    }
    if (i < 16384) {                       // WoT[j][d] = Wo[d][j]
        int j = i >> 7, d = i & 127;
        WoT[i] = Wo[d * 128 + j];
    }
    if (i < 8192) W2bf[i] = f2bf(W2[i]);
}

// ---------- per-b bias: c1[b][n] = b1[n] + sum_j W1diffT[j][n]*q[b][j] ----------
__global__ void c1_kernel(const float* __restrict__ query, const float* __restrict__ W1diffT,
                          const float* __restrict__ b1, float* __restrict__ c1out) {
    __shared__ float qs[128];
    int b = blockIdx.x, t = threadIdx.x;
    if (t < 128) qs[t] = query[b * 128 + t];
    __syncthreads();
    float acc = b1[t];
    #pragma unroll 8
    for (int j = 0; j < 128; ++j) acc += W1diffT[j * 256 + t] * qs[j];
    c1out[b * 256 + t] = acc;
}

// ---------- fused main kernel: one block per batch element ----------
__launch_bounds__(512, 2)
__global__ void attn_kernel(const float* __restrict__ query, const float* __restrict__ keys,
                            const int* __restrict__ kmask,
                            const float* __restrict__ a1, const float* __restrict__ b2,
                            const float* __restrict__ a2, const float* __restrict__ W3,
                            const float* __restrict__ b3, const float* __restrict__ bo,
                            const float* __restrict__ W1sum, const float* __restrict__ W1c,
                            const float* __restrict__ WoT, const ushort_t* __restrict__ W2bf,
                            const float* __restrict__ c1ws, float* __restrict__ out) {
    extern __shared__ char smem[];
    const int tid = threadIdx.x;
    const int bb  = blockIdx.x;
    const int w   = tid >> 6;
    const int l   = tid & 63;
    const int l15 = l & 15;
    const int lk  = l >> 4;

    float* qs   = (float*)(smem + QS_OFF);
    float* b2s  = (float*)(smem + B2S_OFF);
    float* w3s  = (float*)(smem + W3S_OFF);
    float* c1s  = (float*)(smem + C1S_OFF);
    float* scw  = (float*)(smem + SCW_OFF);
    int*   mks  = (int*)(smem + MASK_OFF);
    float* comb = (float*)(smem + COMB_OFF);
    float* a1s  = (float*)(smem + A1S_OFF);
    float* a2s  = (float*)(smem + A2S_OFF);
    float* b3s  = (float*)(smem + B3S_OFF);

    // ---- phase 0a: small stages ----
    if (tid < 128) qs[tid] = query[bb * 128 + tid];
    else if (tid < 256) b2s[tid - 128] = b2[tid - 128];
    else if (tid < 384) w3s[tid - 256] = W3[tid - 256];
    else if (tid < 396) {
        int i = tid - 384;
        if (i < 4) a1s[i] = a1[i];
        else if (i < 8) a2s[i - 4] = a2[i - 4];
        else b3s[i - 8] = b3[i - 8];
    }
    if (tid < SP)  mks[tid] = (tid < Ssz) ? kmask[bb * Ssz + tid] : 0;
    if (tid < 256) c1s[tid] = c1ws[bb * 256 + tid];
    __syncthreads();

    // ---- phase 0b: keys -> bf16 LDS (swizzled), W2 stage, W1eff build ----
    #pragma unroll
    for (int it = 0; it < 14; ++it) {          // 224 rows * 32 float4/row
        int id = tid + 512 * it;
        int row = id >> 5, c4 = id & 31;
        float4 kv = {0.f, 0.f, 0.f, 0.f};
        if (row < Ssz) kv = *(const float4*)(keys + (size_t)(bb * Ssz + row) * Dsz + c4 * 4);
        uint_t p0 = (uint_t)f2bf(kv.x) | ((uint_t)f2bf(kv.y) << 16);
        uint_t p1 = (uint_t)f2bf(kv.z) | ((uint_t)f2bf(kv.w) << 16);
        int off = KEYS_OFF + (((row << 8) + (c4 << 3)) ^ ((row & 7) << 4));
        *(uint_t*)(smem + off)     = p0;
        *(uint_t*)(smem + off + 4) = p1;
    }
    const uint_t* W2u = (const uint_t*)W2bf;
    #pragma unroll
    for (int it = 0; it < 8; ++it) {           // 4096 bf16-pairs
        int p = tid + 512 * it;
        int flat = p * 2;
        int h = flat >> 11, rem = flat & 2047;
        int e = rem >> 6, k = rem & 63;
        int off = W2S_OFF + ((((h << 12) + (e << 7) + (k << 1))) ^ ((e & 7) << 4));
        *(uint_t*)(smem + off) = W2u[p];
    }
    const float2* Ws2 = (const float2*)W1sum;
    const float2* Wc2 = (const float2*)W1c;
    #pragma unroll
    for (int it = 0; it < 32; ++it) {          // 16384 pairs: W1eff = W1sum + W1c*q
        int p = tid + 512 * it;
        int n = p >> 6, jp = p & 63;
        float2 sv = Ws2[p];
        float2 cv = Wc2[p];
        float q0 = qs[jp * 2], q1 = qs[jp * 2 + 1];
        uint_t pk = (uint_t)f2bf(sv.x + cv.x * q0) | ((uint_t)f2bf(sv.y + cv.y * q1) << 16);
        int off = W1EFF_OFF + ((((n << 8) + (jp << 2))) ^ ((n & 7) << 4));
        *(uint_t*)(smem + off) = pk;
    }
    __syncthreads();

    // ---- layer 1: h1 = keys @ W1eff^T  (M=208 pad, N=256, K=128) ----
    const int wr = w >> 2;   // M half: 0 -> tiles 0..6, 1 -> tiles 7..12
    const int wc = w & 3;    // head (64 N-cols)
    const f32x4 fz = {0.f, 0.f, 0.f, 0.f};
    f32x4 acc[7][4];
    #pragma unroll
    for (int m = 0; m < 7; ++m)
        #pragma unroll
        for (int n = 0; n < 4; ++n) acc[m][n] = fz;

    #pragma unroll
    for (int t = 0; t < 4; ++t) {
        short8 bfr[4];
        #pragma unroll
        for (int nt = 0; nt < 4; ++nt) {
            int n = wc * 64 + nt * 16 + l15;
            int off = W1EFF_OFF + ((((n << 8) + (t * 64 + lk * 16))) ^ ((n & 7) << 4));
            bfr[nt] = *(const short8*)(smem + off);
        }
        #pragma unroll
        for (int mt = 0; mt < 7; ++mt) {
            int gmt = wr * 7 + mt;
            if (gmt < 13) {
                int row = gmt * 16 + l15;
                int off = KEYS_OFF + ((((row << 8) + (t * 64 + lk * 16))) ^ ((row & 7) << 4));
                short8 afr = *(const short8*)(smem + off);
                #pragma unroll
                for (int nt = 0; nt < 4; ++nt)
                    acc[mt][nt] = __builtin_amdgcn_mfma_f32_16x16x32_bf16(afr, bfr[nt], acc[mt][nt], 0, 0, 0);
            }
        }
    }

    // ---- layers 2+3, chunked through a 32-row h1 buffer ----
    float c1v[4];
    #pragma unroll
    for (int nt = 0; nt < 4; ++nt) c1v[nt] = c1s[wc * 64 + nt * 16 + l15];
    const float a1v = a1s[wc];
    const int h2  = w >> 1;  // layer-2 head for this wave
    const int mtl = w & 1;   // layer-2 local M tile
    float b2v[2], w3v[2];
    #pragma unroll
    for (int nt = 0; nt < 2; ++nt) {
        b2v[nt] = b2s[h2 * 32 + nt * 16 + l15];
        w3v[nt] = w3s[h2 * 32 + nt * 16 + l15];
    }
    const float a2v = a2s[h2];
    const float b3v = b3s[h2];

    for (int c = 0; c < 7; ++c) {
        // write leaky(h1)+c1 for rows [32c, 32c+32) into h1c (bf16, swizzled)
        #pragma unroll
        for (int mt = 0; mt < 7; ++mt) {
            int gmt = wr * 7 + mt;
            if (gmt < 13 && (gmt == 2 * c || gmt == 2 * c + 1)) {
                int rbase = (gmt - 2 * c) * 16 + lk * 4;
                #pragma unroll
                for (int nt = 0; nt < 4; ++nt) {
                    int n = wc * 64 + nt * 16 + l15;
                    #pragma unroll
                    for (int r = 0; r < 4; ++r) {
                        float v = acc[mt][nt][r] + c1v[nt];
                        v = (v >= 0.f) ? v : a1v * v;
                        int lrow = rbase + r;
                        int off = H1C_OFF + ((((lrow << 9) + (n << 1))) ^ ((lrow & 7) << 4));
                        *(ushort_t*)(smem + off) = f2bf(v);
                    }
                }
            }
        }
        __syncthreads();
        if (c < 6 || mtl == 0) {               // chunk 6 has only 16 rows
            f32x4 acc2[2];
            acc2[0] = fz; acc2[1] = fz;
            #pragma unroll
            for (int kt = 0; kt < 2; ++kt) {
                int lrow = mtl * 16 + l15;
                int k = kt * 32 + lk * 8;
                int aoff = H1C_OFF + ((((lrow << 9) + ((h2 * 64 + k) << 1))) ^ ((lrow & 7) << 4));
                short8 afr = *(const short8*)(smem + aoff);
                #pragma unroll
                for (int nt = 0; nt < 2; ++nt) {
                    int e = nt * 16 + l15;
                    int boff = W2S_OFF + ((((h2 << 12) + (e << 7) + (k << 1))) ^ ((e & 7) << 4));
                    short8 bfr2 = *(const short8*)(smem + boff);
                    acc2[nt] = __builtin_amdgcn_mfma_f32_16x16x32_bf16(afr, bfr2, acc2[nt], 0, 0, 0);
                }
            }
            // layer 3: score = (sum_e leaky(h2+b2)*W3) + b3, *tw, mask
            #pragma unroll
            for (int r = 0; r < 4; ++r) {
                float sum = 0.f;
                #pragma unroll
                for (int nt = 0; nt < 2; ++nt) {
                    float v = acc2[nt][r] + b2v[nt];
                    v = (v >= 0.f) ? v : a2v * v;
                    sum += v * w3v[nt];
                }
                sum += __shfl_xor(sum, 1);
                sum += __shfl_xor(sum, 2);
                sum += __shfl_xor(sum, 4);
                sum += __shfl_xor(sum, 8);
                if (l15 == 0) {
                    int sg = 32 * c + mtl * 16 + lk * 4 + r;
                    float tw = __expf(0.1f * (float)(sg - (Ssz - 1)));
                    float sc = (sum + b3v) * tw;
                    scw[h2 * SP + sg] = mks[sg] ? sc : -1.0e9f;
                }
            }
        }
        __syncthreads();
    }

    // ---- softmax per head (waves 0..3), in place: scores -> weights ----
    if (w < 4) {
        float xv[4], ex[4];
        float mx = -3.0e38f;
        #pragma unroll
        for (int i = 0; i < 4; ++i) {
            int s = l + 64 * i;
            xv[i] = (s < Ssz) ? scw[w * SP + s] : -1.0e30f;
            mx = fmaxf(mx, xv[i]);
        }
        #pragma unroll
        for (int m = 1; m < 64; m <<= 1) mx = fmaxf(mx, __shfl_xor(mx, m));
        float sm = 0.f;
        #pragma unroll
        for (int i = 0; i < 4; ++i) {
            int s = l + 64 * i;
            ex[i] = (s < Ssz) ? __expf(xv[i] - mx) : 0.f;
            sm += ex[i];
        }
        #pragma unroll
        for (int m = 1; m < 64; m <<= 1) sm += __shfl_xor(sm, m);
        float inv = 1.0f / sm;
        #pragma unroll
        for (int i = 0; i < 4; ++i) {
            int s = l + 64 * i;
            if (s < SP) scw[w * SP + s] = ex[i] * inv;  // zeros for s>=200
        }
    }
    __syncthreads();

    // avg_weights output
    if (tid < Ssz) {
        float aw = 0.25f * (scw[tid] + scw[SP + tid] + scw[2 * SP + tid] + scw[3 * SP + tid]);
        out[Bsz * Dsz + bb * Ssz + tid] = aw;
    }

    // ---- PV via MFMA: A = w (heads as rows 0..3), B = keys; wave w -> d cols [16w,16w+16) ----
    f32x4 acc4 = fz;
    #pragma unroll
    for (int t = 0; t < 7; ++t) {
        int k0 = t * 32 + lk * 8;
        short8 afr = {0, 0, 0, 0, 0, 0, 0, 0};
        if (l15 < 4) {
            const float* wp = scw + l15 * SP + k0;
            #pragma unroll
            for (int j = 0; j < 8; ++j) afr[j] = (short)f2bf(wp[j]);
        }
        short8 bfr;
        #pragma unroll
        for (int j = 0; j < 8; ++j) {
            int srow = k0 + j;
            int off = KEYS_OFF + ((((srow << 8) + ((16 * w + l15) << 1))) ^ ((srow & 7) << 4));
            bfr[j] = *(const short*)(smem + off);
        }
        acc4 = __builtin_amdgcn_mfma_f32_16x16x32_bf16(afr, bfr, acc4, 0, 0, 0);
    }
    if (lk == 0) comb[16 * w + l15] = 0.25f * (acc4[0] + acc4[1] + acc4[2] + acc4[3]);
    __syncthreads();

    // ---- output projection: out = combined @ Wo^T + bo (f32 VALU) ----
    if (tid < Dsz) {
        float o = bo[tid];
        #pragma unroll 8
        for (int j = 0; j < Dsz; ++j) o += comb[j] * WoT[j * Dsz + tid];
        out[bb * Dsz + tid] = o;
    }
}

// ws layout (bytes): W1sum 131072 | W1c 131072 | W1diffT 131072 | WoT 65536 |
//                    W2bf 16384 | c1 2097152   => total 2,572,288 required
extern "C" void kernel_launch(void* const* d_in, const int* in_sizes, int n_in,
                              void* d_out, int out_size, void* d_ws, size_t ws_size,
                              hipStream_t stream) {
    const float* query = (const float*)d_in[0];
    const float* keys  = (const float*)d_in[1];
    const int*   kmask = (const int*)d_in[2];
    const float* W1    = (const float*)d_in[3];
    const float* b1    = (const float*)d_in[4];
    const float* a1    = (const float*)d_in[5];
    const float* W2    = (const float*)d_in[6];
    const float* b2    = (const float*)d_in[7];
    const float* a2    = (const float*)d_in[8];
    const float* W3    = (const float*)d_in[9];
    const float* b3    = (const float*)d_in[10];
    const float* Wo    = (const float*)d_in[11];
    const float* bo    = (const float*)d_in[12];
    float* out = (float*)d_out;

    char* ws = (char*)d_ws;
    float*    W1sum   = (float*)(ws);
    float*    W1c     = (float*)(ws + 131072);
    float*    W1diffT = (float*)(ws + 262144);
    float*    WoT     = (float*)(ws + 393216);
    ushort_t* W2bf    = (ushort_t*)(ws + 458752);
    float*    c1ws    = (float*)(ws + 475136);

    hipFuncSetAttribute(reinterpret_cast<const void*>(attn_kernel),
                        hipFuncAttributeMaxDynamicSharedMemorySize, SMEM_BYTES);

    prep_kernel<<<128, 256, 0, stream>>>(W1, W2, Wo, W1sum, W1c, W1diffT, WoT, W2bf);
    c1_kernel<<<Bsz, 256, 0, stream>>>(query, W1diffT, b1, c1ws);
    attn_kernel<<<Bsz, 512, SMEM_BYTES, stream>>>(query, keys, kmask, a1, b2, a2, W3, b3, bo,
                                                  W1sum, W1c, WoT, W2bf, c1ws, out);
}

// Round 2
// 225.420 us; speedup vs baseline: 1.1607x; 1.1607x over previous
//
#include <hip/hip_runtime.h>
#include <hip/hip_bf16.h>
#include <stdint.h>

// Problem constants
#define Bsz 2048
#define Ssz 200
#define Dsz 128
#define Hsz 4
#define SP  224   // padded S (7 K-steps of 32 for PV)
#define SPB 232   // scwb row stride (bf16)

typedef __attribute__((ext_vector_type(8))) short short8;
typedef __attribute__((ext_vector_type(4))) float f32x4;
typedef unsigned short ushort_t;
typedef unsigned int uint_t;

// ---- LDS byte offsets ----
#define KEYS_OFF   0        // [224][128] bf16 swz          57,344
#define W1H_OFF    57344    // W1EFF [256][128] bf16 swz (65,536)
                            //   aliased after layer-1 by H1C [112][256] bf16 swz (57,344)
#define W2S_OFF    122880   // [4][32][64] bf16 swz         16,384
#define SCW_OFF    139264   // [4][224] f32                  3,584
#define SCWB_OFF   142848   // [16][232] bf16 (rows 4..15 = 0)  7,424
#define C1S_OFF    150272   // [256] f32                     1,024
#define QS_OFF     151296   // [128] f32                       512
#define B2S_OFF    151808   // [128] f32                       512
#define W3S_OFF    152320   // [128] f32                       512
#define MASK_OFF   152832   // [224] int                       896
#define COMB_OFF   153728   // [128] f32                       512
#define PO_OFF     154240   // [4][128] f32                  2,048
#define A1S_OFF    156288
#define A2S_OFF    156304
#define B3S_OFF    156320
#define SMEM_BYTES 156336

__device__ __forceinline__ ushort_t f2bf(float x) {
    union { float f; uint_t u; } v; v.f = x;
    uint_t u = v.u;
    u += 0x7FFFu + ((u >> 16) & 1u);   // round-to-nearest-even
    return (ushort_t)(u >> 16);
}

// ---------- prep: fold W1, transpose Wo, cast W2 ----------
__global__ void prep_kernel(const float* __restrict__ W1, const float* __restrict__ W2,
                            const float* __restrict__ Wo,
                            float* __restrict__ W1sum, float* __restrict__ W1c,
                            float* __restrict__ W1diffT, float* __restrict__ WoT,
                            ushort_t* __restrict__ W2bf) {
    int i = blockIdx.x * blockDim.x + threadIdx.x;
    if (i < 32768) {                       // n in [0,256), j in [0,128)
        int n = i >> 7, j = i & 127;
        float a  = W1[n * 512 + j];        // keys part
        float dd = W1[n * 512 + 384 + j];  // (k - q) part
        W1sum[i] = a + dd;                 // coeff of k
        W1c[i]   = W1[n * 512 + 256 + j];  // coeff of k*q
        W1diffT[j * 256 + n] = W1[n * 512 + 128 + j] - dd;  // coeff of q (transposed)
    }
    if (i < 16384) {                       // WoT[j][d] = Wo[d][j]
        int j = i >> 7, d = i & 127;
        WoT[i] = Wo[d * 128 + j];
    }
    if (i < 8192) W2bf[i] = f2bf(W2[i]);
}

// ---------- per-b bias: c1[b][n] = b1[n] + sum_j W1diffT[j][n]*q[b][j] ----------
__global__ void c1_kernel(const float* __restrict__ query, const float* __restrict__ W1diffT,
                          const float* __restrict__ b1, float* __restrict__ c1out) {
    __shared__ float qs[128];
    int b = blockIdx.x, t = threadIdx.x;
    if (t < 128) qs[t] = query[b * 128 + t];
    __syncthreads();
    float acc = b1[t];
    #pragma unroll 8
    for (int j = 0; j < 128; ++j) acc += W1diffT[j * 256 + t] * qs[j];
    c1out[b * 256 + t] = acc;
}

// ---------- fused main kernel: one block per batch element ----------
__launch_bounds__(512, 1)
__global__ void attn_kernel(const float* __restrict__ query, const float* __restrict__ keys,
                            const int* __restrict__ kmask,
                            const float* __restrict__ a1, const float* __restrict__ b2,
                            const float* __restrict__ a2, const float* __restrict__ W3,
                            const float* __restrict__ b3, const float* __restrict__ bo,
                            const float* __restrict__ W1sum, const float* __restrict__ W1c,
                            const float* __restrict__ WoT, const ushort_t* __restrict__ W2bf,
                            const float* __restrict__ c1ws, float* __restrict__ out) {
    extern __shared__ char smem[];
    const int tid = threadIdx.x;
    const int bb  = blockIdx.x;
    const int w   = tid >> 6;
    const int l   = tid & 63;
    const int l15 = l & 15;
    const int lk  = l >> 4;

    float* qs   = (float*)(smem + QS_OFF);
    float* b2s  = (float*)(smem + B2S_OFF);
    float* w3s  = (float*)(smem + W3S_OFF);
    float* c1s  = (float*)(smem + C1S_OFF);
    float* scw  = (float*)(smem + SCW_OFF);
    int*   mks  = (int*)(smem + MASK_OFF);
    float* comb = (float*)(smem + COMB_OFF);
    float* po   = (float*)(smem + PO_OFF);
    float* a1s  = (float*)(smem + A1S_OFF);
    float* a2s  = (float*)(smem + A2S_OFF);
    float* b3s  = (float*)(smem + B3S_OFF);

    // ---- phase 0a: small stages (qs needed by W1eff fold) ----
    if (tid < 128) qs[tid] = query[bb * 128 + tid];
    else if (tid < 256) b2s[tid - 128] = b2[tid - 128];
    else if (tid < 384) w3s[tid - 256] = W3[tid - 256];
    else if (tid < 396) {
        int i = tid - 384;
        if (i < 4) a1s[i] = a1[i];
        else if (i < 8) a2s[i - 4] = a2[i - 4];
        else b3s[i - 8] = b3[i - 8];
    }
    if (tid < SP)  mks[tid] = (tid < Ssz) ? kmask[bb * Ssz + tid] : 0;
    if (tid < 256) c1s[tid] = c1ws[bb * 256 + tid];
    // zero scwb (rows 4..15 must be zero for PV A-fragments)
    {
        uint_t* zb = (uint_t*)(smem + SCWB_OFF);
        for (int i = tid; i < 1856; i += 512) zb[i] = 0;
    }
    __syncthreads();

    // ---- phase 0b: keys -> bf16 LDS (swizzled), W2 stage, W1eff build ----
    #pragma unroll
    for (int it = 0; it < 14; ++it) {          // 224 rows * 32 float4/row
        int id = tid + 512 * it;
        int row = id >> 5, c4 = id & 31;
        float4 kv = {0.f, 0.f, 0.f, 0.f};
        if (row < Ssz) kv = *(const float4*)(keys + (size_t)(bb * Ssz + row) * Dsz + c4 * 4);
        uint_t p0 = (uint_t)f2bf(kv.x) | ((uint_t)f2bf(kv.y) << 16);
        uint_t p1 = (uint_t)f2bf(kv.z) | ((uint_t)f2bf(kv.w) << 16);
        int off = KEYS_OFF + (((row << 8) + (c4 << 3)) ^ ((row & 7) << 4));
        *(uint_t*)(smem + off)     = p0;
        *(uint_t*)(smem + off + 4) = p1;
    }
    const uint_t* W2u = (const uint_t*)W2bf;
    #pragma unroll
    for (int it = 0; it < 8; ++it) {           // 4096 bf16-pairs
        int p = tid + 512 * it;
        int flat = p * 2;
        int h = flat >> 11, rem = flat & 2047;
        int e = rem >> 6, k = rem & 63;
        int off = W2S_OFF + ((((h << 12) + (e << 7) + (k << 1))) ^ ((e & 7) << 4));
        *(uint_t*)(smem + off) = W2u[p];
    }
    const float2* Ws2 = (const float2*)W1sum;
    const float2* Wc2 = (const float2*)W1c;
    #pragma unroll
    for (int it = 0; it < 32; ++it) {          // 16384 pairs: W1eff = W1sum + W1c*q
        int p = tid + 512 * it;
        int n = p >> 6, jp = p & 63;
        float2 sv = Ws2[p];
        float2 cv = Wc2[p];
        float q0 = qs[jp * 2], q1 = qs[jp * 2 + 1];
        uint_t pk = (uint_t)f2bf(sv.x + cv.x * q0) | ((uint_t)f2bf(sv.y + cv.y * q1) << 16);
        int off = W1H_OFF + ((((n << 8) + (jp << 2))) ^ ((n & 7) << 4));
        *(uint_t*)(smem + off) = pk;
    }
    __syncthreads();

    // ---- layer 1: h1 = keys @ W1eff^T  (M=208 pad, N=256, K=128), all in regs ----
    const int wr = w >> 2;   // M half: 0 -> tiles 0..6, 1 -> tiles 7..12
    const int wc = w & 3;    // head (64 N-cols)
    const f32x4 fz = {0.f, 0.f, 0.f, 0.f};
    f32x4 acc[7][4];
    #pragma unroll
    for (int m = 0; m < 7; ++m)
        #pragma unroll
        for (int n = 0; n < 4; ++n) acc[m][n] = fz;

    #pragma unroll
    for (int t = 0; t < 4; ++t) {
        short8 bfr[4];
        #pragma unroll
        for (int nt = 0; nt < 4; ++nt) {
            int n = wc * 64 + nt * 16 + l15;
            int off = W1H_OFF + ((((n << 8) + (t * 64 + lk * 16))) ^ ((n & 7) << 4));
            bfr[nt] = *(const short8*)(smem + off);
        }
        #pragma unroll
        for (int mt = 0; mt < 7; ++mt) {
            int gmt = wr * 7 + mt;
            if (gmt < 13) {
                int row = gmt * 16 + l15;
                int off = KEYS_OFF + ((((row << 8) + (t * 64 + lk * 16))) ^ ((row & 7) << 4));
                short8 afr = *(const short8*)(smem + off);
                #pragma unroll
                for (int nt = 0; nt < 4; ++nt)
                    acc[mt][nt] = __builtin_amdgcn_mfma_f32_16x16x32_bf16(afr, bfr[nt], acc[mt][nt], 0, 0, 0);
            }
        }
    }
    __syncthreads();   // W1EFF region now dead -> reuse as H1C

    // ---- layers 2+3 in TWO chunks (chunk c = wr-half c's rows) ----
    float c1v[4];
    #pragma unroll
    for (int nt = 0; nt < 4; ++nt) c1v[nt] = c1s[wc * 64 + nt * 16 + l15];
    const float a1v = a1s[wc];
    const int h2 = w >> 1;   // layer-2 head for this wave
    float b2v[2], w3v[2];
    #pragma unroll
    for (int nt = 0; nt < 2; ++nt) {
        b2v[nt] = b2s[h2 * 32 + nt * 16 + l15];
        w3v[nt] = w3s[h2 * 32 + nt * 16 + l15];
    }
    const float a2v = a2s[h2];
    const float b3v = b3s[h2];

    #pragma unroll
    for (int c = 0; c < 2; ++c) {
        const int TT = (c == 0) ? 7 : 6;       // tiles in this chunk
        // write leaky(h1)+c1 for this chunk's rows into H1C (bf16, swizzled)
        if (wr == c) {
            #pragma unroll
            for (int mt = 0; mt < 7; ++mt) {
                if (mt < TT) {
                    int rbase = mt * 16 + lk * 4;
                    #pragma unroll
                    for (int nt = 0; nt < 4; ++nt) {
                        int n = wc * 64 + nt * 16 + l15;
                        #pragma unroll
                        for (int r = 0; r < 4; ++r) {
                            float v = acc[mt][nt][r] + c1v[nt];
                            v = (v >= 0.f) ? v : a1v * v;
                            int lrow = rbase + r;
                            int off = W1H_OFF + ((((lrow << 9) + (n << 1))) ^ ((lrow & 7) << 4));
                            *(ushort_t*)(smem + off) = f2bf(v);
                        }
                    }
                }
            }
        }
        __syncthreads();
        // layer 2+3 over this chunk: wave w handles head h2, tiles (w&1), (w&1)+2, ...
        for (int t2 = (w & 1); t2 < TT; t2 += 2) {
            f32x4 acc2[2];
            acc2[0] = fz; acc2[1] = fz;
            #pragma unroll
            for (int kt = 0; kt < 2; ++kt) {
                int lrow = t2 * 16 + l15;
                int k = kt * 32 + lk * 8;
                int aoff = W1H_OFF + ((((lrow << 9) + ((h2 * 64 + k) << 1))) ^ ((lrow & 7) << 4));
                short8 afr = *(const short8*)(smem + aoff);
                #pragma unroll
                for (int nt = 0; nt < 2; ++nt) {
                    int e = nt * 16 + l15;
                    int boff = W2S_OFF + ((((h2 << 12) + (e << 7) + (k << 1))) ^ ((e & 7) << 4));
                    short8 bfr2 = *(const short8*)(smem + boff);
                    acc2[nt] = __builtin_amdgcn_mfma_f32_16x16x32_bf16(afr, bfr2, acc2[nt], 0, 0, 0);
                }
            }
            #pragma unroll
            for (int r = 0; r < 4; ++r) {
                float sum = 0.f;
                #pragma unroll
                for (int nt = 0; nt < 2; ++nt) {
                    float v = acc2[nt][r] + b2v[nt];
                    v = (v >= 0.f) ? v : a2v * v;
                    sum += v * w3v[nt];
                }
                sum += __shfl_xor(sum, 1);
                sum += __shfl_xor(sum, 2);
                sum += __shfl_xor(sum, 4);
                sum += __shfl_xor(sum, 8);
                if (l15 == 0) {
                    int sg = c * 112 + t2 * 16 + lk * 4 + r;
                    float tw = __expf(0.1f * (float)(sg - (Ssz - 1)));
                    float sc = (sum + b3v) * tw;
                    scw[h2 * SP + sg] = mks[sg] ? sc : -1.0e9f;
                }
            }
        }
        __syncthreads();
    }

    // ---- softmax per head (waves 0..3): scores -> weights (f32 + packed bf16) ----
    if (w < 4) {
        float xv[4], ex[4];
        float mx = -3.0e38f;
        #pragma unroll
        for (int i = 0; i < 4; ++i) {
            int s = l + 64 * i;
            xv[i] = (s < Ssz) ? scw[w * SP + s] : -1.0e30f;
            mx = fmaxf(mx, xv[i]);
        }
        #pragma unroll
        for (int m = 1; m < 64; m <<= 1) mx = fmaxf(mx, __shfl_xor(mx, m));
        float sm = 0.f;
        #pragma unroll
        for (int i = 0; i < 4; ++i) {
            int s = l + 64 * i;
            ex[i] = (s < Ssz) ? __expf(xv[i] - mx) : 0.f;
            sm += ex[i];
        }
        #pragma unroll
        for (int m = 1; m < 64; m <<= 1) sm += __shfl_xor(sm, m);
        float inv = 1.0f / sm;
        #pragma unroll
        for (int i = 0; i < 4; ++i) {
            int s = l + 64 * i;
            float wv = ex[i] * inv;
            if (s < SP) scw[w * SP + s] = wv;                                  // f32 (avg out)
            if (s < SPB) *(ushort_t*)(smem + SCWB_OFF + w * (SPB * 2) + s * 2) = f2bf(wv);
        }
    }
    __syncthreads();

    // avg_weights output (reads f32 weights)
    if (tid < Ssz) {
        float aw = 0.25f * (scw[tid] + scw[SP + tid] + scw[2 * SP + tid] + scw[3 * SP + tid]);
        out[Bsz * Dsz + bb * Ssz + tid] = aw;
    }

    // ---- PV via MFMA: A = weights (rows 0..3 = heads), B = keys; wave w -> d cols [16w,16w+16) ----
    f32x4 acc4 = fz;
    #pragma unroll
    for (int t = 0; t < 7; ++t) {
        int k0 = t * 32 + lk * 8;
        short8 afr = *(const short8*)(smem + SCWB_OFF + l15 * (SPB * 2) + k0 * 2);
        short8 bfr;
        #pragma unroll
        for (int j = 0; j < 8; ++j) {
            int srow = k0 + j;
            int off = KEYS_OFF + ((((srow << 8) + ((16 * w + l15) << 1))) ^ ((srow & 7) << 4));
            bfr[j] = *(const short*)(smem + off);
        }
        acc4 = __builtin_amdgcn_mfma_f32_16x16x32_bf16(afr, bfr, acc4, 0, 0, 0);
    }
    if (lk == 0) comb[16 * w + l15] = 0.25f * (acc4[0] + acc4[1] + acc4[2] + acc4[3]);
    __syncthreads();

    // ---- output projection, all 512 threads: d = tid&127, j-range = (tid>>7)*32 ----
    {
        int d = tid & 127, part = tid >> 7;
        float o = 0.f;
        const float* wp = WoT + (size_t)part * 32 * 128 + d;
        #pragma unroll 8
        for (int j = 0; j < 32; ++j) o += comb[part * 32 + j] * wp[j * 128];
        po[part * 128 + d] = o;
    }
    __syncthreads();
    if (tid < Dsz) {
        out[bb * Dsz + tid] = bo[tid] + po[tid] + po[128 + tid] + po[256 + tid] + po[384 + tid];
    }
}

// ws layout (bytes): W1sum 131072 | W1c 131072 | W1diffT 131072 | WoT 65536 |
//                    W2bf 16384 | c1 2097152   => total 2,572,288 required
extern "C" void kernel_launch(void* const* d_in, const int* in_sizes, int n_in,
                              void* d_out, int out_size, void* d_ws, size_t ws_size,
                              hipStream_t stream) {
    const float* query = (const float*)d_in[0];
    const float* keys  = (const float*)d_in[1];
    const int*   kmask = (const int*)d_in[2];
    const float* W1    = (const float*)d_in[3];
    const float* b1    = (const float*)d_in[4];
    const float* a1    = (const float*)d_in[5];
    const float* W2    = (const float*)d_in[6];
    const float* b2    = (const float*)d_in[7];
    const float* a2    = (const float*)d_in[8];
    const float* W3    = (const float*)d_in[9];
    const float* b3    = (const float*)d_in[10];
    const float* Wo    = (const float*)d_in[11];
    const float* bo    = (const float*)d_in[12];
    float* out = (float*)d_out;

    char* ws = (char*)d_ws;
    float*    W1sum   = (float*)(ws);
    float*    W1c     = (float*)(ws + 131072);
    float*    W1diffT = (float*)(ws + 262144);
    float*    WoT     = (float*)(ws + 393216);
    ushort_t* W2bf    = (ushort_t*)(ws + 458752);
    float*    c1ws    = (float*)(ws + 475136);

    hipFuncSetAttribute(reinterpret_cast<const void*>(attn_kernel),
                        hipFuncAttributeMaxDynamicSharedMemorySize, SMEM_BYTES);

    prep_kernel<<<128, 256, 0, stream>>>(W1, W2, Wo, W1sum, W1c, W1diffT, WoT, W2bf);
    c1_kernel<<<Bsz, 256, 0, stream>>>(query, W1diffT, b1, c1ws);
    attn_kernel<<<Bsz, 512, SMEM_BYTES, stream>>>(query, keys, kmask, a1, b2, a2, W3, b3, bo,
                                                  W1sum, W1c, WoT, W2bf, c1ws, out);
}